// Round 12
// baseline (286.770 us; speedup 1.0000x reference)
//
#include <hip/hip_runtime.h>

// Sparse 3D conv (K=3, stride=2, pad=1), dense output, OUTPUT-ROW GATHER.
// No global atomics, no output memset, 3 dispatches.
// Inputs: features [N,32] f32, W [3,3,3,32,64] f32, coors [N,4] i32 (b,z,y,x).
// Output: [B,64,64,64,64] f32 flat, every element written exactly once.
// ws: [ map B*128^3 i32 (voxel -> point chain head) | nxt N i32 ]

#define CIN   32
#define COUT  64
#define OUTD  64
#define IND   128
#define RPB   4          // output rows per block
#define NTH   512        // threads per block (8 waves)
#define WSTR  20         // wfu u32 stride per ch (padded: 40 ushorts) -> bank spread
#define NPTS  128
#define NBLK  2048

// ---------- map build: voxel -> head of point-index chain (R3-verified) ----------
__global__ void build_map(const int4* __restrict__ coors, int* __restrict__ map,
                          int* __restrict__ nxt, int N)
{
    int i = blockIdx.x * 256 + threadIdx.x;
    if (i >= N) return;
    const int4 c = coors[i];                       // (b, z, y, x)
    const int v = ((c.x * IND + c.y) * IND + c.z) * IND + c.w;
    nxt[i] = atomicExch(&map[v], i);               // chain handles duplicate coords
}

// ---------- gather: block = 4 consecutive output x-rows ----------
__global__ __launch_bounds__(NTH) void row_gather(
    const float* __restrict__ feats, const float* __restrict__ W,
    const int* __restrict__ map, const int* __restrict__ nxt,
    float* __restrict__ out)
{
    __shared__ __align__(16) float    accf[RPB * 64 * COUT];   // 64 KB
    __shared__ __align__(16) unsigned wfu[3 * 64 * WSTR];      // 15 KB [kx][ch][c/2]

    const int tid = threadIdx.x;
    const int ch  = tid & 63;        // lane: out channel (and px probe index)
    const int wv  = tid >> 6;        // wave 0..7
    const int row0 = blockIdx.x * RPB;             // rows share (b, oz): row0 % 64 <= 60
    const int b   = row0 >> 12;
    const int oz  = (row0 >> 6) & 63;
    const int oy0 = row0 & 63;

    for (int i = tid; i < RPB * 64 * COUT; i += NTH) accf[i] = 0.f;

    for (int s = 0; s < 9; ++s) {
        const int kz = s / 3, ky = s % 3;
        const int pz = 2 * oz - 1 + kz;
        const bool sv = ((unsigned)pz < IND);
        __syncthreads();                           // wf free to overwrite; acc zero visible

        if (sv) {                                  // stage site W: 3 kx slices -> bf16 LDS
            const float* Ws = W + ((kz * 3 + ky) * 3) * (CIN * COUT);
            for (int i = tid; i < 3 * 64 * 16; i += NTH) {
                const int chh = i & 63;
                const int cp  = (i >> 6) & 15;
                const int kx  = i >> 10;
                const unsigned u0 = __float_as_uint(Ws[kx * 2048 + (2 * cp) * 64 + chh]);
                const unsigned u1 = __float_as_uint(Ws[kx * 2048 + (2 * cp + 1) * 64 + chh]);
                const unsigned b0 = (u0 + 0x7fffu + ((u0 >> 16) & 1u)) >> 16;   // RNE
                const unsigned b1 = (u1 + 0x7fffu + ((u1 >> 16) & 1u)) >> 16;
                wfu[(kx * 64 + chh) * WSTR + cp] = b0 | (b1 << 16);
            }
        }
        __syncthreads();
        if (!sv) continue;

        for (int r = 0; r < RPB; ++r) {
            const int py = 2 * (oy0 + r) - 1 + ky;
            if ((unsigned)py >= IND) continue;
            const int* rowp = map + ((b * IND + pz) * IND + py) * IND;
            const int2 mv = ((const int2*)rowp)[ch];       // lane L covers px=2L,2L+1
            const unsigned long long bE = __ballot(mv.x >= 0);
            const unsigned long long bO = __ballot(mv.y >= 0);
            int cnt = 0;

            // even px = 2L: kx=1, ox=L (always valid)
            for (unsigned long long m = bE; m; m &= m - 1, ++cnt) {
                if ((cnt & 7) != wv) continue;
                const int L = __builtin_ctzll(m);
                int j = __shfl(mv.x, L);
                while (j >= 0) {
                    const float4* fp = (const float4*)(feats + (size_t)j * CIN);
                    float4 f[8];
                    #pragma unroll
                    for (int q = 0; q < 8; ++q) f[q] = fp[q];
                    {
                        const uint4* wq = (const uint4*)(wfu + (1 * 64 + ch) * WSTR);
                        float s0 = 0.f, s1 = 0.f;
                        #pragma unroll
                        for (int q = 0; q < 4; ++q) {
                            const uint4 w4 = wq[q];
                            const float4 fa = f[2 * q], fb = f[2 * q + 1];
                            s0 += fa.x * __uint_as_float(w4.x << 16);
                            s1 += fa.y * __uint_as_float(w4.x & 0xffff0000u);
                            s0 += fa.z * __uint_as_float(w4.y << 16);
                            s1 += fa.w * __uint_as_float(w4.y & 0xffff0000u);
                            s0 += fb.x * __uint_as_float(w4.z << 16);
                            s1 += fb.y * __uint_as_float(w4.z & 0xffff0000u);
                            s0 += fb.z * __uint_as_float(w4.w << 16);
                            s1 += fb.w * __uint_as_float(w4.w & 0xffff0000u);
                        }
                        unsafeAtomicAdd(&accf[(r * 64 + L) * COUT + ch], s0 + s1);
                    }
                    j = nxt[j];
                }
            }
            // odd px = 2L+1: kx=2 -> ox=L; kx=0 -> ox=L+1 (if L<63)
            for (unsigned long long m = bO; m; m &= m - 1, ++cnt) {
                if ((cnt & 7) != wv) continue;
                const int L = __builtin_ctzll(m);
                int j = __shfl(mv.y, L);
                while (j >= 0) {
                    const float4* fp = (const float4*)(feats + (size_t)j * CIN);
                    float4 f[8];
                    #pragma unroll
                    for (int q = 0; q < 8; ++q) f[q] = fp[q];
                    {
                        const uint4* wq = (const uint4*)(wfu + (2 * 64 + ch) * WSTR);
                        float s0 = 0.f, s1 = 0.f;
                        #pragma unroll
                        for (int q = 0; q < 4; ++q) {
                            const uint4 w4 = wq[q];
                            const float4 fa = f[2 * q], fb = f[2 * q + 1];
                            s0 += fa.x * __uint_as_float(w4.x << 16);
                            s1 += fa.y * __uint_as_float(w4.x & 0xffff0000u);
                            s0 += fa.z * __uint_as_float(w4.y << 16);
                            s1 += fa.w * __uint_as_float(w4.y & 0xffff0000u);
                            s0 += fb.x * __uint_as_float(w4.z << 16);
                            s1 += fb.y * __uint_as_float(w4.z & 0xffff0000u);
                            s0 += fb.z * __uint_as_float(w4.w << 16);
                            s1 += fb.w * __uint_as_float(w4.w & 0xffff0000u);
                        }
                        unsafeAtomicAdd(&accf[(r * 64 + L) * COUT + ch], s0 + s1);
                    }
                    if (L < 63) {
                        const uint4* wq = (const uint4*)(wfu + (0 * 64 + ch) * WSTR);
                        float s0 = 0.f, s1 = 0.f;
                        #pragma unroll
                        for (int q = 0; q < 4; ++q) {
                            const uint4 w4 = wq[q];
                            const float4 fa = f[2 * q], fb = f[2 * q + 1];
                            s0 += fa.x * __uint_as_float(w4.x << 16);
                            s1 += fa.y * __uint_as_float(w4.x & 0xffff0000u);
                            s0 += fa.z * __uint_as_float(w4.y << 16);
                            s1 += fa.w * __uint_as_float(w4.y & 0xffff0000u);
                            s0 += fb.x * __uint_as_float(w4.z << 16);
                            s1 += fb.y * __uint_as_float(w4.z & 0xffff0000u);
                            s0 += fb.z * __uint_as_float(w4.w << 16);
                            s1 += fb.w * __uint_as_float(w4.w & 0xffff0000u);
                        }
                        unsafeAtomicAdd(&accf[(r * 64 + L + 1) * COUT + ch], s0 + s1);
                    }
                    j = nxt[j];
                }
            }
        }
    }
    __syncthreads();

    // Write 4 rows = 64 KB contiguous, exactly once, float4-coalesced.
    float* op = out + (size_t)row0 * (64 * COUT);
    #pragma unroll
    for (int it = 0; it < 8; ++it) {
        const int i = (it * NTH + tid) * 4;
        *(float4*)(op + i) = *(const float4*)(accf + i);
    }
}

// ---------- fallback A (ws >= 110 KB): R7 champion scatter ----------
__global__ void conv_w_bf16(const float* __restrict__ W, ushort* __restrict__ wsW)
{
    const int k = blockIdx.x;
    for (int i = threadIdx.x; i < CIN * COUT; i += 256) {
        const int c = i >> 6, chh = i & 63;
        const unsigned u = __float_as_uint(W[k * CIN * COUT + i]);
        const unsigned r = (u + 0x7fffu + ((u >> 16) & 1u)) >> 16;
        wsW[(k << 11) + (chh << 5) + c] = (ushort)r;
    }
}

__device__ __forceinline__ int axis_opts(int p, int* k, int* o) {
    int cnt = 0;
    const int kp = (p + 1) & 1;
    const int o0 = (p + 1 - kp) >> 1;
    if (o0 < OUTD) { k[cnt] = kp; o[cnt] = o0; ++cnt; }
    if (kp == 0) { const int o1 = o0 - 1; if (o1 >= 0) { k[cnt] = 2; o[cnt] = o1; ++cnt; } }
    return cnt;
}

__global__ __launch_bounds__(256) void scatter2(
    const float* __restrict__ feats, const ushort* __restrict__ wsW,
    const int4* __restrict__ coors, float* __restrict__ out,
    int N, int totWaves)
{
    const int chh = threadIdx.x & 63;
    const int wv = __builtin_amdgcn_readfirstlane(threadIdx.x >> 6);
    const int gwave = blockIdx.x * 4 + wv;
    for (int i = gwave; i < N; i += totWaves) {
        const int4 c = coors[i];
        const float4* fp = (const float4*)(feats + (size_t)i * CIN);
        float4 f[8];
        #pragma unroll
        for (int q = 0; q < 8; ++q) f[q] = fp[q];
        int kz[2], oz[2], ky[2], oy[2], kx[2], ox[2];
        const int nz = axis_opts(c.y, kz, oz);
        const int ny = axis_opts(c.z, ky, oy);
        const int nx = axis_opts(c.w, kx, ox);
        for (int az = 0; az < nz; ++az)
        for (int ay = 0; ay < ny; ++ay)
        for (int ax = 0; ax < nx; ++ax) {
            const int kidx = (kz[az] * 3 + ky[ay]) * 3 + kx[ax];
            const uint4* wp = (const uint4*)(wsW + (kidx << 11) + (chh << 5));
            uint4 w4[4];
            #pragma unroll
            for (int q = 0; q < 4; ++q) w4[q] = wp[q];
            float s0 = 0.f, s1 = 0.f;
            #pragma unroll
            for (int q = 0; q < 4; ++q) {
                const uint4 wq = w4[q];
                const float4 fa = f[2 * q], fb = f[2 * q + 1];
                s0 += fa.x * __uint_as_float(wq.x << 16);
                s1 += fa.y * __uint_as_float(wq.x & 0xffff0000u);
                s0 += fa.z * __uint_as_float(wq.y << 16);
                s1 += fa.w * __uint_as_float(wq.y & 0xffff0000u);
                s0 += fb.x * __uint_as_float(wq.z << 16);
                s1 += fb.y * __uint_as_float(wq.z & 0xffff0000u);
                s0 += fb.z * __uint_as_float(wq.w << 16);
                s1 += fb.w * __uint_as_float(wq.w & 0xffff0000u);
            }
            const size_t flat = (((size_t)c.x * OUTD + oz[az]) * OUTD + oy[ay]) * OUTD + ox[ax];
            unsafeAtomicAdd(out + flat * COUT + chh, s0 + s1);
        }
    }
}

// ---------- last-resort fallback ----------
__global__ __launch_bounds__(256, 4) void spconv_scatter(
    const float* __restrict__ feats, const float* __restrict__ Wt,
    const int* __restrict__ coors, float* __restrict__ out, int N)
{
    __shared__ float sf[NPTS][CIN];
    __shared__ int   sc[NPTS][4];
    __shared__ int   vf[NPTS];
    const int tid = threadIdx.x;
    const int chh = tid & 63;
    const int wv  = tid >> 6;
    const int base = blockIdx.x * NPTS;
    const int npts = min(NPTS, (int)(blockIdx.x * NPTS < N ? N - base : 0));
    if (npts <= 0) return;
    for (int i = tid; i < npts * CIN; i += 256) sf[0][i] = feats[base * CIN + i];
    for (int i = tid; i < npts * 4; i += 256) ((int*)sc)[i] = coors[base * 4 + i];
    __syncthreads();
    for (int off = 0; off < 27; ++off) {
        const int kz = off / 9, ky = (off / 3) % 3, kx = off % 3;
        if (tid < npts) {
            const int p  = tid;
            const int nz = sc[p][1] + 1 - kz;
            const int ny = sc[p][2] + 1 - ky;
            const int nx = sc[p][3] + 1 - kx;
            const int m  = nz | ny | nx;
            const int oz = nz >> 1, oy = ny >> 1, ox = nx >> 1;
            const bool v = ((m & 0x80000001) == 0) &&
                           (oz < OUTD) && (oy < OUTD) && (ox < OUTD);
            vf[p] = v ? (((sc[p][0] * OUTD + oz) * OUTD + oy) * OUTD + ox) : -1;
        }
        const float* wp = Wt + off * (CIN * COUT) + chh;
        float w[CIN];
        #pragma unroll
        for (int c = 0; c < CIN; ++c) w[c] = wp[c * COUT];
        __syncthreads();
        for (int p = wv; p < npts; p += 4) {
            const int f = vf[p];
            if (f >= 0) {
                float s = 0.f;
                #pragma unroll
                for (int c = 0; c < CIN; ++c) s += sf[p][c] * w[c];
                atomicAdd(&out[(size_t)f * COUT + chh], s);
            }
        }
        __syncthreads();
    }
}

extern "C" void kernel_launch(void* const* d_in, const int* in_sizes, int n_in,
                              void* d_out, int out_size, void* d_ws, size_t ws_size,
                              hipStream_t stream) {
    const float* feats = (const float*)d_in[0];
    const float* Wt    = (const float*)d_in[1];
    const int*   coors = (const int*)d_in[2];
    float*       out   = (float*)d_out;

    const int N = in_sizes[0] / CIN;
    const int B = out_size / (OUTD * OUTD * OUTD * COUT);

    const size_t mapElems = (size_t)B * IND * IND * IND;
    const size_t needMap  = (mapElems + (size_t)N) * sizeof(int);
    const size_t needBf   = 27 * CIN * COUT * sizeof(ushort);

    if (ws_size >= needMap) {
        int* map = (int*)d_ws;
        int* nxt = map + mapElems;
        hipMemsetAsync(map, 0xFF, mapElems * sizeof(int), stream);
        build_map<<<(N + 255) / 256, 256, 0, stream>>>((const int4*)coors, map, nxt, N);
        const int nRows = B * OUTD * OUTD;         // 8192 for B=2
        row_gather<<<nRows / RPB, NTH, 0, stream>>>(feats, Wt, map, nxt, out);
    } else if (ws_size >= needBf) {
        hipMemsetAsync(d_out, 0, (size_t)out_size * sizeof(float), stream);
        ushort* wsW = (ushort*)d_ws;
        conv_w_bf16<<<27, 256, 0, stream>>>(Wt, wsW);
        scatter2<<<NBLK, 256, 0, stream>>>(feats, wsW, (const int4*)coors, out, N, NBLK * 4);
    } else {
        hipMemsetAsync(d_out, 0, (size_t)out_size * sizeof(float), stream);
        spconv_scatter<<<(N + NPTS - 1) / NPTS, 256, 0, stream>>>(feats, Wt, coors, out, N);
    }
}